// Round 10
// baseline (288.452 us; speedup 1.0000x reference)
//
#include <hip/hip_runtime.h>
#include <hip/hip_bf16.h>

#define SEQ    4096
#define CDIM   512
#define NHEADS 8
#define HDIM   64
// fold softmax scale and log2(e) into Q once: exp(s*SCALE) == exp2(s')
#define QSCALE 0.18033688f   // 0.125 * 1.4426950408889634

typedef __attribute__((ext_vector_type(4))) float f32x4;
typedef __attribute__((ext_vector_type(8))) short bf16x8;

// LDS swizzle for tiles with 64-bf16 (128B) row stride: spread rows across banks.
__device__ __forceinline__ int swz(int row, int col) {
    int b = (row << 7) + (col << 1);
    b ^= (row & 7) << 4;
    return b >> 1;
}

__device__ __forceinline__ short f2bf(float f) {
    union { __hip_bfloat16 h; short s; } u;
    u.h = __float2bfloat16(f);
    return u.s;
}

// async global->LDS, 16B per lane; LDS dest = wave-uniform base + lane*16
__device__ __forceinline__ void gl16(const void* g, void* l) {
    __builtin_amdgcn_global_load_lds(
        (const __attribute__((address_space(1))) unsigned int*)g,
        (__attribute__((address_space(3))) unsigned int*)l,
        16, 0, 0);
}

// ---------------- f32 -> bf16 pre-pass (memory-bound, grid-stride)
__global__ __launch_bounds__(256) void cvt_k(
    const float* __restrict__ a, short* __restrict__ o, int n4)
{
    int i = blockIdx.x * 256 + threadIdx.x;
    const int stride = gridDim.x * 256;
    for (; i < n4; i += stride) {
        float4 v = ((const float4*)a)[i];
        short4 r;
        r.x = f2bf(v.x); r.y = f2bf(v.y); r.z = f2bf(v.z); r.w = f2bf(v.w);
        ((short4*)o)[i] = r;
    }
}

// ---------------- QKV GEMM (bf16 inputs): xb[8192,512] @ wb[1536,512]^T
__global__ __launch_bounds__(256) void qkv_gemm_k(
    const short* __restrict__ xb, const short* __restrict__ wb,
    short* __restrict__ qb, short* __restrict__ kb, short* __restrict__ vtb)
{
    __shared__ alignas(16) short As[2][128 * 64];
    __shared__ alignas(16) short Bs[2][128 * 64];
    const int tid  = threadIdx.x;
    const int lane = tid & 63;
    const int l15  = lane & 15;
    const int lg   = lane >> 4;
    const int wv   = tid >> 6;
    const int wy   = wv >> 1, wx = wv & 1;
    const int m0 = blockIdx.x * 128;
    const int n0 = blockIdx.y * 128;

    const f32x4 fzero = {0.f, 0.f, 0.f, 0.f};
    f32x4 acc[4][4];
    #pragma unroll
    for (int i = 0; i < 4; ++i)
        #pragma unroll
        for (int j = 0; j < 4; ++j)
            acc[i][j] = fzero;

    const int row0 = wv * 8 + (lane >> 3);
    const int cb   = ((lane & 7) ^ (lane >> 3)) << 4;
    const char* agp = (const char*)xb + (size_t)(m0 + row0) * 1024 + cb;
    const char* bgp = (const char*)wb + (size_t)(n0 + row0) * 1024 + cb;
    char* al0 = (char*)&As[0][0] + wv * 1024;
    char* al1 = (char*)&As[1][0] + wv * 1024;
    char* bl0 = (char*)&Bs[0][0] + wv * 1024;
    char* bl1 = (char*)&Bs[1][0] + wv * 1024;

    #define QSTAGE(al, bl, kofs) do {                                  \
        _Pragma("unroll")                                              \
        for (int i_ = 0; i_ < 4; ++i_) {                               \
            gl16(agp + (kofs) + i_ * 32768, (al) + i_ * 4096);         \
            gl16(bgp + (kofs) + i_ * 32768, (bl) + i_ * 4096);         \
        } } while (0)

    QSTAGE(al0, bl0, 0);

    int cur = 0;
    for (int k0 = 0; k0 < CDIM; k0 += 64) {
        asm volatile("s_waitcnt vmcnt(0)" ::: "memory");
        __syncthreads();
        if (k0 + 64 < CDIM) {
            if (cur == 0) QSTAGE(al1, bl1, (k0 + 64) * 2);
            else          QSTAGE(al0, bl0, (k0 + 64) * 2);
        }
        const short* Ac = cur ? &As[1][0] : &As[0][0];
        const short* Bc = cur ? &Bs[1][0] : &Bs[0][0];

        #pragma unroll
        for (int ks = 0; ks < 2; ++ks) {
            bf16x8 afr[4], bfr[4];
            #pragma unroll
            for (int i = 0; i < 4; ++i) {
                afr[i] = *(const bf16x8*)(&Ac[swz(wy * 64 + i * 16 + l15, ks * 32 + lg * 8)]);
                bfr[i] = *(const bf16x8*)(&Bc[swz(wx * 64 + i * 16 + l15, ks * 32 + lg * 8)]);
            }
            #pragma unroll
            for (int i = 0; i < 4; ++i)
                #pragma unroll
                for (int j = 0; j < 4; ++j)
                    acc[i][j] = __builtin_amdgcn_mfma_f32_16x16x32_bf16(afr[i], bfr[j], acc[i][j], 0, 0, 0);
        }
        cur ^= 1;
    }
    #undef QSTAGE

    // epilogue: Q (scaled), K as [bh][n][64]; V^T blocked with col-perm
    #pragma unroll
    for (int j = 0; j < 4; ++j) {
        const int d = n0 + wx * 64 + j * 16 + l15;
        const int s = d >> 9;
        const int h = (d >> 6) & 7;
        const int e = d & 63;
        #pragma unroll
        for (int i = 0; i < 4; ++i) {
            #pragma unroll
            for (int r = 0; r < 4; ++r) {
                const int m  = m0 + wy * 64 + i * 16 + lg * 4 + r;
                const int bb = m >> 12;
                const int n  = m & (SEQ - 1);
                const int bh = bb * NHEADS + h;
                const float v = acc[i][j][r];
                if (s == 0) {
                    qb[(((size_t)bh * SEQ + n) << 6) + e] = f2bf(v * QSCALE);
                } else if (s == 1) {
                    kb[(((size_t)bh * SEQ + n) << 6) + e] = f2bf(v);
                } else {
                    // permute within-64 kv index: c=[ks|h|lg|j] -> c'=[ks|lg|h|j]
                    const int c  = n & 63;
                    const int cp = (c & 0x23) | ((c & 0x0C) << 1) | ((c & 0x10) >> 2);
                    vtb[((size_t)bh << 18) + ((size_t)(n >> 6) << 12) + (e << 6) + cp] = f2bf(v);
                }
            }
        }
    }
}

// ---------------- Flash attention v6: split-KV + cross-tile pipeline.
//   Tile t's exp2 overlaps tile t-1's PV (independent). K double-buffered,
//   V TRIPLE-buffered so stage(t+1) never hits the buffer PV(t-1) reads.
//   2 wave-groups (kv halves) x 4 waves; 80KB LDS -> 2 blocks/CU, VGPR<=128.
__global__ __launch_bounds__(512, 4) void attn_k(
    const short* __restrict__ qb, const short* __restrict__ kb, const short* __restrict__ vtb,
    short* __restrict__ ob)
{
    __shared__ alignas(16) char smem[81920];
    const int tid  = threadIdx.x;
    const int lane = tid & 63;
    const int l15  = lane & 15;
    const int lg   = lane >> 4;
    const int wv   = (tid >> 6) & 3;    // wave within group
    const int wg   = tid >> 8;          // wave group = kv half
    const int lin  = blockIdx.x;
    const int bh   = lin & 15;          // same-bh blocks land on one XCD (L2 locality)
    const int q0   = (lin >> 4) << 7;   // 128 q-rows per block
    const int b    = bh >> 3, h = bh & 7;
    const size_t base = (size_t)bh * SEQ * HDIM;

    // Q fragments: wave owns 32 q-rows (2 fragments of 16); both groups same Q
    bf16x8 qf[2][2];
    #pragma unroll
    for (int qi = 0; qi < 2; ++qi) {
        const short* qp = qb + base + (size_t)(q0 + wv * 32 + qi * 16 + l15) * HDIM + lg * 8;
        qf[qi][0] = *(const bf16x8*)(qp);
        qf[qi][1] = *(const bf16x8*)(qp + 32);
    }

    const f32x4 fzero = {0.f, 0.f, 0.f, 0.f};
    f32x4 acc[2][4];    // partial O for this kv half
    f32x4 lacc[2];      // partial row sums via ones-MFMA
    #pragma unroll
    for (int qi = 0; qi < 2; ++qi) {
        lacc[qi] = fzero;
        #pragma unroll
        for (int di = 0; di < 4; ++di) acc[qi][di] = fzero;
    }

    bf16x8 ones;
    #pragma unroll
    for (int e = 0; e < 8; ++e) ones[e] = (short)0x3F80;  // bf16 1.0

    // staging: per-group 8KB K dbuf x2 + 8KB V x3; slot t = wv*128 + i*64 + lane
    const int t0  = wv * 128 + lane;
    const int cbs = ((t0 & 7) ^ ((t0 >> 3) & 7)) << 4;
    const int ghb = wg * 262144;   // group's kv-half byte offset (2048 kv * 128B)
    const char* kgp = (const char*)(kb + base) + ghb + (((t0 >> 3) << 7) + cbs);
    const char* vgp = (const char*)(vtb + ((size_t)bh << 18)) + ghb + (((t0 >> 3) << 7) + cbs);
    char* const gb = smem + wg * 40960;
    // stage dest (per-wave), read bases (group-wide)
    char* K0p = gb +     0 + wv * 2048;  const short* Kr0 = (const short*)(gb);
    char* K1p = gb +  8192 + wv * 2048;  const short* Kr1 = (const short*)(gb + 8192);
    char* V0p = gb + 16384 + wv * 2048;  const short* Vr0 = (const short*)(gb + 16384);
    char* V1p = gb + 24576 + wv * 2048;  const short* Vr1 = (const short*)(gb + 24576);
    char* V2p = gb + 32768 + wv * 2048;  const short* Vr2 = (const short*)(gb + 32768);

    bf16x8 paA[2][2], paB[2][2];

    #define STAGE(klp, vlp, TI) do {                                       \
        _Pragma("unroll")                                                  \
        for (int i_ = 0; i_ < 2; ++i_) {                                   \
            gl16(kgp + (TI) * 8192 + i_ * 1024, (klp) + i_ * 1024);        \
            gl16(vgp + (TI) * 8192 + i_ * 1024, (vlp) + i_ * 1024);        \
        } } while (0)

    // QK(t) -> s ; PV(t-1) with PAP interleaved 4-MFMA/8-exp2 with exp2(t)->PAN
    #define BODY(TILE, KRD, VPR, KSTP, VSTP, PAP, PAN, DOSTG) do {         \
        asm volatile("s_waitcnt vmcnt(0)" ::: "memory");                   \
        __syncthreads();                                                   \
        if (DOSTG) { STAGE(KSTP, VSTP, (TILE) + 1); }                      \
        f32x4 s[2][4];                                                     \
        _Pragma("unroll")                                                  \
        for (int qi = 0; qi < 2; ++qi)                                     \
            _Pragma("unroll")                                              \
            for (int ni = 0; ni < 4; ++ni) s[qi][ni] = fzero;              \
        _Pragma("unroll")                                                  \
        for (int kk = 0; kk < 2; ++kk)                                     \
            _Pragma("unroll")                                              \
            for (int ni = 0; ni < 4; ++ni) {                               \
                bf16x8 kf = *(const bf16x8*)(&(KRD)[swz(ni * 16 + l15, kk * 32 + lg * 8)]); \
                s[0][ni] = __builtin_amdgcn_mfma_f32_16x16x32_bf16(kf, qf[0][kk], s[0][ni], 0, 0, 0); \
                s[1][ni] = __builtin_amdgcn_mfma_f32_16x16x32_bf16(kf, qf[1][kk], s[1][ni], 0, 0, 0); \
            }                                                              \
        _Pragma("unroll")                                                  \
        for (int dd = 0; dd < 4; ++dd) {                                   \
            bf16x8 v0 = *(const bf16x8*)(&(VPR)[swz(dd * 16 + l15, lg * 8)]);      \
            bf16x8 v1 = *(const bf16x8*)(&(VPR)[swz(dd * 16 + l15, 32 + lg * 8)]); \
            acc[0][dd] = __builtin_amdgcn_mfma_f32_16x16x32_bf16(PAP[0][0], v0, acc[0][dd], 0, 0, 0); \
            acc[0][dd] = __builtin_amdgcn_mfma_f32_16x16x32_bf16(PAP[0][1], v1, acc[0][dd], 0, 0, 0); \
            acc[1][dd] = __builtin_amdgcn_mfma_f32_16x16x32_bf16(PAP[1][0], v0, acc[1][dd], 0, 0, 0); \
            acc[1][dd] = __builtin_amdgcn_mfma_f32_16x16x32_bf16(PAP[1][1], v1, acc[1][dd], 0, 0, 0); \
            _Pragma("unroll")                                              \
            for (int e = 0; e < 8; ++e)                                    \
                PAN[dd >> 1][dd & 1][e] = f2bf(__builtin_amdgcn_exp2f(     \
                    s[dd >> 1][(dd & 1) * 2 + (e >> 2)][e & 3]));          \
        }                                                                  \
        lacc[0] = __builtin_amdgcn_mfma_f32_16x16x32_bf16(PAP[0][0], ones, lacc[0], 0, 0, 0); \
        lacc[0] = __builtin_amdgcn_mfma_f32_16x16x32_bf16(PAP[0][1], ones, lacc[0], 0, 0, 0); \
        lacc[1] = __builtin_amdgcn_mfma_f32_16x16x32_bf16(PAP[1][0], ones, lacc[1], 0, 0, 0); \
        lacc[1] = __builtin_amdgcn_mfma_f32_16x16x32_bf16(PAP[1][1], ones, lacc[1], 0, 0, 0); \
    } while (0)

    // prologue: tile 0 (QK + exp2 only)
    STAGE(K0p, V0p, 0);
    asm volatile("s_waitcnt vmcnt(0)" ::: "memory");
    __syncthreads();
    STAGE(K1p, V1p, 1);
    {
        f32x4 s[2][4];
        #pragma unroll
        for (int qi = 0; qi < 2; ++qi)
            #pragma unroll
            for (int ni = 0; ni < 4; ++ni) s[qi][ni] = fzero;
        #pragma unroll
        for (int kk = 0; kk < 2; ++kk)
            #pragma unroll
            for (int ni = 0; ni < 4; ++ni) {
                bf16x8 kf = *(const bf16x8*)(&Kr0[swz(ni * 16 + l15, kk * 32 + lg * 8)]);
                s[0][ni] = __builtin_amdgcn_mfma_f32_16x16x32_bf16(kf, qf[0][kk], s[0][ni], 0, 0, 0);
                s[1][ni] = __builtin_amdgcn_mfma_f32_16x16x32_bf16(kf, qf[1][kk], s[1][ni], 0, 0, 0);
            }
        #pragma unroll
        for (int qi = 0; qi < 2; ++qi)
            #pragma unroll
            for (int ni = 0; ni < 4; ++ni)
                #pragma unroll
                for (int r = 0; r < 4; ++r)
                    paA[qi][ni >> 1][(ni & 1) * 4 + r] =
                        f2bf(__builtin_amdgcn_exp2f(s[qi][ni][r]));
    }

    // main: tiles 1..30 in 6-unrolled groups (periodic buffer pattern), then 31
    for (int i = 0; i < 5; ++i) {
        const int T = 6 * i + 1;
        BODY(T,     Kr1, Vr0, K0p, V2p, paA, paB, 1);
        BODY(T + 1, Kr0, Vr1, K1p, V0p, paB, paA, 1);
        BODY(T + 2, Kr1, Vr2, K0p, V1p, paA, paB, 1);
        BODY(T + 3, Kr0, Vr0, K1p, V2p, paB, paA, 1);
        BODY(T + 4, Kr1, Vr1, K0p, V0p, paA, paB, 1);
        BODY(T + 5, Kr0, Vr2, K1p, V1p, paB, paA, 1);
    }
    BODY(31, Kr1, Vr0, K0p, V2p, paA, paB, 0);

    // epilogue PV for tile 31 (pa(31)=paB, V[31%3]=Vr1)
    #pragma unroll
    for (int dd = 0; dd < 4; ++dd) {
        bf16x8 v0 = *(const bf16x8*)(&Vr1[swz(dd * 16 + l15, lg * 8)]);
        bf16x8 v1 = *(const bf16x8*)(&Vr1[swz(dd * 16 + l15, 32 + lg * 8)]);
        acc[0][dd] = __builtin_amdgcn_mfma_f32_16x16x32_bf16(paB[0][0], v0, acc[0][dd], 0, 0, 0);
        acc[0][dd] = __builtin_amdgcn_mfma_f32_16x16x32_bf16(paB[0][1], v1, acc[0][dd], 0, 0, 0);
        acc[1][dd] = __builtin_amdgcn_mfma_f32_16x16x32_bf16(paB[1][0], v0, acc[1][dd], 0, 0, 0);
        acc[1][dd] = __builtin_amdgcn_mfma_f32_16x16x32_bf16(paB[1][1], v1, acc[1][dd], 0, 0, 0);
    }
    lacc[0] = __builtin_amdgcn_mfma_f32_16x16x32_bf16(paB[0][0], ones, lacc[0], 0, 0, 0);
    lacc[0] = __builtin_amdgcn_mfma_f32_16x16x32_bf16(paB[0][1], ones, lacc[0], 0, 0, 0);
    lacc[1] = __builtin_amdgcn_mfma_f32_16x16x32_bf16(paB[1][0], ones, lacc[1], 0, 0, 0);
    lacc[1] = __builtin_amdgcn_mfma_f32_16x16x32_bf16(paB[1][1], ones, lacc[1], 0, 0, 0);
    #undef BODY
    #undef STAGE

    // ---- combine the two kv-halves: O = (O0+O1)/(l0+l1) ----
    __syncthreads();   // all K/V reads done; smem reusable as f32 exchange buffer
    float* xch = (float*)smem;
    const int xi = (wv * 64 + lane) * 44;   // 44 f32 stride: 16B-aligned, bank-spread
    if (wg == 1) {
        #pragma unroll
        for (int qi = 0; qi < 2; ++qi) {
            #pragma unroll
            for (int di = 0; di < 4; ++di)
                *(f32x4*)(xch + xi + qi * 16 + di * 4) = acc[qi][di];
            *(f32x4*)(xch + xi + 32 + qi * 4) = lacc[qi];
        }
    }
    __syncthreads();
    if (wg == 0) {
        #pragma unroll
        for (int qi = 0; qi < 2; ++qi) {
            #pragma unroll
            for (int di = 0; di < 4; ++di)
                acc[qi][di] += *(const f32x4*)(xch + xi + qi * 16 + di * 4);
            lacc[qi] += *(const f32x4*)(xch + xi + 32 + qi * 4);
        }
        #pragma unroll
        for (int qi = 0; qi < 2; ++qi) {
            float inv[4];
            #pragma unroll
            for (int r = 0; r < 4; ++r) inv[r] = 1.0f / lacc[qi][r];
            #pragma unroll
            for (int di = 0; di < 4; ++di) {
                const int e = di * 16 + l15;
                #pragma unroll
                for (int r = 0; r < 4; ++r) {
                    const int qn = q0 + wv * 32 + qi * 16 + lg * 4 + r;
                    ob[((size_t)(b * SEQ + qn) << 9) + h * 64 + e] = f2bf(acc[qi][di][r] * inv[r]);
                }
            }
        }
    }
}

// ---------------- proj GEMM (bf16 via gload_lds) + bias + residual: y = x + ao@w^T + bp
__global__ __launch_bounds__(256) void proj_k(
    const short* __restrict__ ao, const short* __restrict__ wpb,
    const float* __restrict__ bp, const float* __restrict__ x,
    float* __restrict__ y)
{
    __shared__ alignas(16) short As[2][128 * 64];
    __shared__ alignas(16) short Bs[2][128 * 64];
    const int tid  = threadIdx.x;
    const int lane = tid & 63;
    const int l15  = lane & 15;
    const int lg   = lane >> 4;
    const int wv   = tid >> 6;
    const int wy   = wv >> 1, wx = wv & 1;
    const int m0 = blockIdx.x * 128;
    const int n0 = blockIdx.y * 128;

    const f32x4 fzero = {0.f, 0.f, 0.f, 0.f};
    f32x4 acc[4][4];
    #pragma unroll
    for (int i = 0; i < 4; ++i)
        #pragma unroll
        for (int j = 0; j < 4; ++j)
            acc[i][j] = fzero;

    const int row0 = wv * 8 + (lane >> 3);
    const int cb   = ((lane & 7) ^ (lane >> 3)) << 4;
    const char* agp = (const char*)ao  + (size_t)(m0 + row0) * 1024 + cb;
    const char* bgp = (const char*)wpb + (size_t)(n0 + row0) * 1024 + cb;
    char* al0 = (char*)&As[0][0] + wv * 1024;
    char* al1 = (char*)&As[1][0] + wv * 1024;
    char* bl0 = (char*)&Bs[0][0] + wv * 1024;
    char* bl1 = (char*)&Bs[1][0] + wv * 1024;

    #define PSTAGE(al, bl, kofs) do {                                  \
        _Pragma("unroll")                                              \
        for (int i_ = 0; i_ < 4; ++i_) {                               \
            gl16(agp + (kofs) + i_ * 32768, (al) + i_ * 4096);         \
            gl16(bgp + (kofs) + i_ * 32768, (bl) + i_ * 4096);         \
        } } while (0)

    PSTAGE(al0, bl0, 0);

    int cur = 0;
    for (int k0 = 0; k0 < CDIM; k0 += 64) {
        asm volatile("s_waitcnt vmcnt(0)" ::: "memory");
        __syncthreads();
        if (k0 + 64 < CDIM) {
            if (cur == 0) PSTAGE(al1, bl1, (k0 + 64) * 2);
            else          PSTAGE(al0, bl0, (k0 + 64) * 2);
        }
        const short* Ac = cur ? &As[1][0] : &As[0][0];
        const short* Bc = cur ? &Bs[1][0] : &Bs[0][0];

        #pragma unroll
        for (int ks = 0; ks < 2; ++ks) {
            bf16x8 afr[4], bfr[4];
            #pragma unroll
            for (int i = 0; i < 4; ++i) {
                afr[i] = *(const bf16x8*)(&Ac[swz(wy * 64 + i * 16 + l15, ks * 32 + lg * 8)]);
                bfr[i] = *(const bf16x8*)(&Bc[swz(wx * 64 + i * 16 + l15, ks * 32 + lg * 8)]);
            }
            #pragma unroll
            for (int i = 0; i < 4; ++i)
                #pragma unroll
                for (int j = 0; j < 4; ++j)
                    acc[i][j] = __builtin_amdgcn_mfma_f32_16x16x32_bf16(afr[i], bfr[j], acc[i][j], 0, 0, 0);
        }
        cur ^= 1;
    }
    #undef PSTAGE

    #pragma unroll
    for (int i = 0; i < 4; ++i) {
        #pragma unroll
        for (int j = 0; j < 4; ++j) {
            const int d = n0 + wx * 64 + j * 16 + l15;
            #pragma unroll
            for (int r = 0; r < 4; ++r) {
                const int m = m0 + wy * 64 + i * 16 + lg * 4 + r;
                const size_t idx = (size_t)m * CDIM + d;
                y[idx] = acc[i][j][r] + bp[d] + x[idx];
            }
        }
    }
}

// ---------------- LayerNorm in place over d_out rows (512 f32 each), 1 wave/row
__global__ __launch_bounds__(256) void ln_k(
    float* __restrict__ y, const float* __restrict__ gm, const float* __restrict__ bt)
{
    const int lane = threadIdx.x & 63;
    const int row  = blockIdx.x * 4 + (threadIdx.x >> 6);
    float* p = y + (size_t)row * CDIM;
    float4 a = *(const float4*)(p + lane * 4);
    float4 b = *(const float4*)(p + 256 + lane * 4);
    float s = a.x + a.y + a.z + a.w + b.x + b.y + b.z + b.w;
    float q = a.x * a.x + a.y * a.y + a.z * a.z + a.w * a.w
            + b.x * b.x + b.y * b.y + b.z * b.z + b.w * b.w;
    #pragma unroll
    for (int mm = 1; mm < 64; mm <<= 1) {
        s += __shfl_xor(s, mm, 64);
        q += __shfl_xor(q, mm, 64);
    }
    const float mean = s * (1.0f / CDIM);
    const float var  = q * (1.0f / CDIM) - mean * mean;
    const float inv  = rsqrtf(var + 1e-5f);
    float4 g0 = *(const float4*)(gm + lane * 4);
    float4 g1 = *(const float4*)(gm + 256 + lane * 4);
    float4 t0 = *(const float4*)(bt + lane * 4);
    float4 t1 = *(const float4*)(bt + 256 + lane * 4);
    float4 r0, r1;
    r0.x = (a.x - mean) * inv * g0.x + t0.x;
    r0.y = (a.y - mean) * inv * g0.y + t0.y;
    r0.z = (a.z - mean) * inv * g0.z + t0.z;
    r0.w = (a.w - mean) * inv * g0.w + t0.w;
    r1.x = (b.x - mean) * inv * g1.x + t1.x;
    r1.y = (b.y - mean) * inv * g1.y + t1.y;
    r1.z = (b.z - mean) * inv * g1.z + t1.z;
    r1.w = (b.w - mean) * inv * g1.w + t1.w;
    *(float4*)(p + lane * 4) = r0;
    *(float4*)(p + 256 + lane * 4) = r1;
}

extern "C" void kernel_launch(void* const* d_in, const int* in_sizes, int n_in,
                              void* d_out, int out_size, void* d_ws, size_t ws_size,
                              hipStream_t stream)
{
    const float* x      = (const float*)d_in[0];
    const float* w_qkv  = (const float*)d_in[1];
    const float* w_proj = (const float*)d_in[2];
    const float* b_proj = (const float*)d_in[3];
    const float* gamma  = (const float*)d_in[4];
    const float* beta   = (const float*)d_in[5];
    float* out = (float*)d_out;

    const size_t qkv_elems = (size_t)16 * SEQ * HDIM;
    short* qb    = (short*)d_ws;
    short* kb    = qb + qkv_elems;
    short* vtb   = kb + qkv_elems;
    short* ob    = vtb + qkv_elems;
    short* xb    = ob;                     // alias: xb dead before attn writes ob
    short* wqkvb = ob + qkv_elems;
    short* wpb   = qb;                     // alias: qb dead after attn

    cvt_k     <<<dim3(1024),   256, 0, stream>>>(x, xb, (2 * SEQ * CDIM) / 4);
    cvt_k     <<<dim3(256),    256, 0, stream>>>(w_qkv, wqkvb, (3 * CDIM * CDIM) / 4);
    qkv_gemm_k<<<dim3(64, 12), 256, 0, stream>>>(xb, wqkvb, qb, kb, vtb);
    attn_k    <<<dim3(512),    512, 0, stream>>>(qb, kb, vtb, ob);
    cvt_k     <<<dim3(256),    256, 0, stream>>>(w_proj, wpb, (CDIM * CDIM) / 4);
    proj_k    <<<dim3(64, 4),  256, 0, stream>>>(ob, wpb, b_proj, x, out);
    ln_k      <<<dim3(2048),   256, 0, stream>>>(out, gamma, beta);
}

// Round 11
// 121.926 us; speedup vs baseline: 2.3658x; 2.3658x over previous
//
#include <hip/hip_runtime.h>
#include <hip/hip_bf16.h>

#define SEQ    4096
#define CDIM   512
#define NHEADS 8
#define HDIM   64
// fold softmax scale and log2(e) into Q once: exp(s*SCALE) == exp2(s')
#define QSCALE 0.18033688f   // 0.125 * 1.4426950408889634

typedef __attribute__((ext_vector_type(4))) float f32x4;
typedef __attribute__((ext_vector_type(8))) short bf16x8;

// LDS swizzle for tiles with 64-bf16 (128B) row stride: spread rows across banks.
__device__ __forceinline__ int swz(int row, int col) {
    int b = (row << 7) + (col << 1);
    b ^= (row & 7) << 4;
    return b >> 1;
}

__device__ __forceinline__ short f2bf(float f) {
    union { __hip_bfloat16 h; short s; } u;
    u.h = __float2bfloat16(f);
    return u.s;
}

// async global->LDS, 16B per lane; LDS dest = wave-uniform base + lane*16
__device__ __forceinline__ void gl16(const void* g, void* l) {
    __builtin_amdgcn_global_load_lds(
        (const __attribute__((address_space(1))) unsigned int*)g,
        (__attribute__((address_space(3))) unsigned int*)l,
        16, 0, 0);
}

// ---------------- f32 -> bf16 pre-pass (memory-bound, grid-stride)
__global__ __launch_bounds__(256) void cvt_k(
    const float* __restrict__ a, short* __restrict__ o, int n4)
{
    int i = blockIdx.x * 256 + threadIdx.x;
    const int stride = gridDim.x * 256;
    for (; i < n4; i += stride) {
        float4 v = ((const float4*)a)[i];
        short4 r;
        r.x = f2bf(v.x); r.y = f2bf(v.y); r.z = f2bf(v.z); r.w = f2bf(v.w);
        ((short4*)o)[i] = r;
    }
}

// ---------------- QKV GEMM (bf16 inputs): xb[8192,512] @ wb[1536,512]^T
__global__ __launch_bounds__(256) void qkv_gemm_k(
    const short* __restrict__ xb, const short* __restrict__ wb,
    short* __restrict__ qb, short* __restrict__ kb, short* __restrict__ vtb)
{
    __shared__ alignas(16) short As[2][128 * 64];
    __shared__ alignas(16) short Bs[2][128 * 64];
    const int tid  = threadIdx.x;
    const int lane = tid & 63;
    const int l15  = lane & 15;
    const int lg   = lane >> 4;
    const int wv   = tid >> 6;
    const int wy   = wv >> 1, wx = wv & 1;
    const int m0 = blockIdx.x * 128;
    const int n0 = blockIdx.y * 128;

    const f32x4 fzero = {0.f, 0.f, 0.f, 0.f};
    f32x4 acc[4][4];
    #pragma unroll
    for (int i = 0; i < 4; ++i)
        #pragma unroll
        for (int j = 0; j < 4; ++j)
            acc[i][j] = fzero;

    const int row0 = wv * 8 + (lane >> 3);
    const int cb   = ((lane & 7) ^ (lane >> 3)) << 4;
    const char* agp = (const char*)xb + (size_t)(m0 + row0) * 1024 + cb;
    const char* bgp = (const char*)wb + (size_t)(n0 + row0) * 1024 + cb;
    char* al0 = (char*)&As[0][0] + wv * 1024;
    char* al1 = (char*)&As[1][0] + wv * 1024;
    char* bl0 = (char*)&Bs[0][0] + wv * 1024;
    char* bl1 = (char*)&Bs[1][0] + wv * 1024;

    #define QSTAGE(al, bl, kofs) do {                                  \
        _Pragma("unroll")                                              \
        for (int i_ = 0; i_ < 4; ++i_) {                               \
            gl16(agp + (kofs) + i_ * 32768, (al) + i_ * 4096);         \
            gl16(bgp + (kofs) + i_ * 32768, (bl) + i_ * 4096);         \
        } } while (0)

    QSTAGE(al0, bl0, 0);

    int cur = 0;
    for (int k0 = 0; k0 < CDIM; k0 += 64) {
        asm volatile("s_waitcnt vmcnt(0)" ::: "memory");
        __syncthreads();
        if (k0 + 64 < CDIM) {
            if (cur == 0) QSTAGE(al1, bl1, (k0 + 64) * 2);
            else          QSTAGE(al0, bl0, (k0 + 64) * 2);
        }
        const short* Ac = cur ? &As[1][0] : &As[0][0];
        const short* Bc = cur ? &Bs[1][0] : &Bs[0][0];

        #pragma unroll
        for (int ks = 0; ks < 2; ++ks) {
            bf16x8 afr[4], bfr[4];
            #pragma unroll
            for (int i = 0; i < 4; ++i) {
                afr[i] = *(const bf16x8*)(&Ac[swz(wy * 64 + i * 16 + l15, ks * 32 + lg * 8)]);
                bfr[i] = *(const bf16x8*)(&Bc[swz(wx * 64 + i * 16 + l15, ks * 32 + lg * 8)]);
            }
            #pragma unroll
            for (int i = 0; i < 4; ++i)
                #pragma unroll
                for (int j = 0; j < 4; ++j)
                    acc[i][j] = __builtin_amdgcn_mfma_f32_16x16x32_bf16(afr[i], bfr[j], acc[i][j], 0, 0, 0);
        }
        cur ^= 1;
    }
    #undef QSTAGE

    // epilogue: Q (scaled), K as [bh][n][64]; V^T blocked with col-perm
    #pragma unroll
    for (int j = 0; j < 4; ++j) {
        const int d = n0 + wx * 64 + j * 16 + l15;
        const int s = d >> 9;
        const int h = (d >> 6) & 7;
        const int e = d & 63;
        #pragma unroll
        for (int i = 0; i < 4; ++i) {
            #pragma unroll
            for (int r = 0; r < 4; ++r) {
                const int m  = m0 + wy * 64 + i * 16 + lg * 4 + r;
                const int bb = m >> 12;
                const int n  = m & (SEQ - 1);
                const int bh = bb * NHEADS + h;
                const float v = acc[i][j][r];
                if (s == 0) {
                    qb[(((size_t)bh * SEQ + n) << 6) + e] = f2bf(v * QSCALE);
                } else if (s == 1) {
                    kb[(((size_t)bh * SEQ + n) << 6) + e] = f2bf(v);
                } else {
                    // permute within-64 kv index: c=[ks|h|lg|j] -> c'=[ks|lg|h|j]
                    const int c  = n & 63;
                    const int cp = (c & 0x23) | ((c & 0x0C) << 1) | ((c & 0x10) >> 2);
                    vtb[((size_t)bh << 18) + ((size_t)(n >> 6) << 12) + (e << 6) + cp] = f2bf(v);
                }
            }
        }
    }
}

// ---------------- Flash attention v7: split-KV + cross-tile pipeline,
//   liveness-reduced: QK->exp2 fused per-ni (s never materializes as array),
//   PV(t-1) MFMAs interleaved between QK(ni) and exp2(ni).
//   K double-buffered, V triple-buffered. 80KB LDS -> 2 blocks/CU.
__global__ __launch_bounds__(512) void attn_k(
    const short* __restrict__ qb, const short* __restrict__ kb, const short* __restrict__ vtb,
    short* __restrict__ ob)
{
    __shared__ alignas(16) char smem[81920];
    const int tid  = threadIdx.x;
    const int lane = tid & 63;
    const int l15  = lane & 15;
    const int lg   = lane >> 4;
    const int wv   = (tid >> 6) & 3;    // wave within group
    const int wg   = tid >> 8;          // wave group = kv half
    const int lin  = blockIdx.x;
    const int bh   = lin & 15;          // same-bh blocks land on one XCD (L2 locality)
    const int q0   = (lin >> 4) << 7;   // 128 q-rows per block
    const int b    = bh >> 3, h = bh & 7;
    const size_t base = (size_t)bh * SEQ * HDIM;

    // Q fragments: wave owns 32 q-rows (2 fragments of 16); both groups same Q
    bf16x8 qf[2][2];
    #pragma unroll
    for (int qi = 0; qi < 2; ++qi) {
        const short* qp = qb + base + (size_t)(q0 + wv * 32 + qi * 16 + l15) * HDIM + lg * 8;
        qf[qi][0] = *(const bf16x8*)(qp);
        qf[qi][1] = *(const bf16x8*)(qp + 32);
    }

    const f32x4 fzero = {0.f, 0.f, 0.f, 0.f};
    f32x4 acc[2][4];    // partial O for this kv half
    f32x4 lacc[2];      // partial row sums via ones-MFMA
    #pragma unroll
    for (int qi = 0; qi < 2; ++qi) {
        lacc[qi] = fzero;
        #pragma unroll
        for (int di = 0; di < 4; ++di) acc[qi][di] = fzero;
    }

    bf16x8 ones;
    #pragma unroll
    for (int e = 0; e < 8; ++e) ones[e] = (short)0x3F80;  // bf16 1.0

    // staging: per-group 8KB K dbuf x2 + 8KB V x3; slot t = wv*128 + i*64 + lane
    const int t0  = wv * 128 + lane;
    const int cbs = ((t0 & 7) ^ ((t0 >> 3) & 7)) << 4;
    const int ghb = wg * 262144;   // group's kv-half byte offset (2048 kv * 128B)
    const char* kgp = (const char*)(kb + base) + ghb + (((t0 >> 3) << 7) + cbs);
    const char* vgp = (const char*)(vtb + ((size_t)bh << 18)) + ghb + (((t0 >> 3) << 7) + cbs);
    char* const gb = smem + wg * 40960;
    char* K0p = gb +     0 + wv * 2048;  const short* Kr0 = (const short*)(gb);
    char* K1p = gb +  8192 + wv * 2048;  const short* Kr1 = (const short*)(gb + 8192);
    char* V0p = gb + 16384 + wv * 2048;  const short* Vr0 = (const short*)(gb + 16384);
    char* V1p = gb + 24576 + wv * 2048;  const short* Vr1 = (const short*)(gb + 24576);
    char* V2p = gb + 32768 + wv * 2048;  const short* Vr2 = (const short*)(gb + 32768);

    bf16x8 paA[2][2], paB[2][2];

    #define STAGE(klp, vlp, TI) do {                                       \
        _Pragma("unroll")                                                  \
        for (int i_ = 0; i_ < 2; ++i_) {                                   \
            gl16(kgp + (TI) * 8192 + i_ * 1024, (klp) + i_ * 1024);        \
            gl16(vgp + (TI) * 8192 + i_ * 1024, (vlp) + i_ * 1024);        \
        } } while (0)

    #define MFMA16(a_, b_, c_) __builtin_amdgcn_mfma_f32_16x16x32_bf16(a_, b_, c_, 0, 0, 0)

    // BODY(t): QK(ni)->exp2(ni) fused, PV(t-1) MFMAs interleaved between them.
    #define BODY(TILE, KRD, VPR, KSTP, VSTP, PAP, PAN, DOSTG) do {             \
        asm volatile("s_waitcnt vmcnt(0)" ::: "memory");                       \
        __syncthreads();                                                       \
        if (DOSTG) { STAGE(KSTP, VSTP, (TILE) + 1); }                          \
        _Pragma("unroll")                                                      \
        for (int ni = 0; ni < 4; ++ni) {                                       \
            bf16x8 kf0 = *(const bf16x8*)(&(KRD)[swz(ni * 16 + l15, lg * 8)]);      \
            bf16x8 kf1 = *(const bf16x8*)(&(KRD)[swz(ni * 16 + l15, 32 + lg * 8)]); \
            f32x4 s0 = fzero, s1 = fzero;                                      \
            s0 = MFMA16(kf0, qf[0][0], s0);                                    \
            s0 = MFMA16(kf1, qf[0][1], s0);                                    \
            s1 = MFMA16(kf0, qf[1][0], s1);                                    \
            s1 = MFMA16(kf1, qf[1][1], s1);                                    \
            bf16x8 v0 = *(const bf16x8*)(&(VPR)[swz(ni * 16 + l15, lg * 8)]);       \
            bf16x8 v1 = *(const bf16x8*)(&(VPR)[swz(ni * 16 + l15, 32 + lg * 8)]);  \
            acc[0][ni] = MFMA16(PAP[0][0], v0, acc[0][ni]);                    \
            acc[0][ni] = MFMA16(PAP[0][1], v1, acc[0][ni]);                    \
            acc[1][ni] = MFMA16(PAP[1][0], v0, acc[1][ni]);                    \
            acc[1][ni] = MFMA16(PAP[1][1], v1, acc[1][ni]);                    \
            if (ni == 0) { lacc[0] = MFMA16(PAP[0][0], ones, lacc[0]);         \
                           lacc[0] = MFMA16(PAP[0][1], ones, lacc[0]); }       \
            if (ni == 1) { lacc[1] = MFMA16(PAP[1][0], ones, lacc[1]);         \
                           lacc[1] = MFMA16(PAP[1][1], ones, lacc[1]); }       \
            _Pragma("unroll")                                                  \
            for (int r = 0; r < 4; ++r) {                                      \
                PAN[0][ni >> 1][(ni & 1) * 4 + r] = f2bf(__builtin_amdgcn_exp2f(s0[r])); \
                PAN[1][ni >> 1][(ni & 1) * 4 + r] = f2bf(__builtin_amdgcn_exp2f(s1[r])); \
            }                                                                  \
        }                                                                      \
    } while (0)

    // prologue: tile 0 (QK + exp2 only, into paA)
    STAGE(K0p, V0p, 0);
    asm volatile("s_waitcnt vmcnt(0)" ::: "memory");
    __syncthreads();
    STAGE(K1p, V1p, 1);
    #pragma unroll
    for (int ni = 0; ni < 4; ++ni) {
        bf16x8 kf0 = *(const bf16x8*)(&Kr0[swz(ni * 16 + l15, lg * 8)]);
        bf16x8 kf1 = *(const bf16x8*)(&Kr0[swz(ni * 16 + l15, 32 + lg * 8)]);
        f32x4 s0 = fzero, s1 = fzero;
        s0 = MFMA16(kf0, qf[0][0], s0);
        s0 = MFMA16(kf1, qf[0][1], s0);
        s1 = MFMA16(kf0, qf[1][0], s1);
        s1 = MFMA16(kf1, qf[1][1], s1);
        #pragma unroll
        for (int r = 0; r < 4; ++r) {
            paA[0][ni >> 1][(ni & 1) * 4 + r] = f2bf(__builtin_amdgcn_exp2f(s0[r]));
            paA[1][ni >> 1][(ni & 1) * 4 + r] = f2bf(__builtin_amdgcn_exp2f(s1[r]));
        }
    }

    // main: tiles 1..30 in 6-unrolled groups (periodic buffer pattern), then 31
    for (int i = 0; i < 5; ++i) {
        BODY(6 * i + 1, Kr1, Vr0, K0p, V2p, paA, paB, 1);
        BODY(6 * i + 2, Kr0, Vr1, K1p, V0p, paB, paA, 1);
        BODY(6 * i + 3, Kr1, Vr2, K0p, V1p, paA, paB, 1);
        BODY(6 * i + 4, Kr0, Vr0, K1p, V2p, paB, paA, 1);
        BODY(6 * i + 5, Kr1, Vr1, K0p, V0p, paA, paB, 1);
        BODY(6 * i + 6, Kr0, Vr2, K1p, V1p, paB, paA, 1);
    }
    BODY(31, Kr1, Vr0, K0p, V2p, paA, paB, 0);

    // epilogue PV for tile 31 (pa(31)=paB, V[31%3]=Vr1)
    #pragma unroll
    for (int dd = 0; dd < 4; ++dd) {
        bf16x8 v0 = *(const bf16x8*)(&Vr1[swz(dd * 16 + l15, lg * 8)]);
        bf16x8 v1 = *(const bf16x8*)(&Vr1[swz(dd * 16 + l15, 32 + lg * 8)]);
        acc[0][dd] = MFMA16(paB[0][0], v0, acc[0][dd]);
        acc[0][dd] = MFMA16(paB[0][1], v1, acc[0][dd]);
        acc[1][dd] = MFMA16(paB[1][0], v0, acc[1][dd]);
        acc[1][dd] = MFMA16(paB[1][1], v1, acc[1][dd]);
    }
    lacc[0] = MFMA16(paB[0][0], ones, lacc[0]);
    lacc[0] = MFMA16(paB[0][1], ones, lacc[0]);
    lacc[1] = MFMA16(paB[1][0], ones, lacc[1]);
    lacc[1] = MFMA16(paB[1][1], ones, lacc[1]);
    #undef BODY
    #undef MFMA16
    #undef STAGE

    // ---- combine the two kv-halves: O = (O0+O1)/(l0+l1) ----
    __syncthreads();   // all K/V reads done; smem reusable as f32 exchange buffer
    float* xch = (float*)smem;
    const int xi = (wv * 64 + lane) * 44;   // 44 f32 stride: 16B-aligned, bank-spread
    if (wg == 1) {
        #pragma unroll
        for (int qi = 0; qi < 2; ++qi) {
            #pragma unroll
            for (int di = 0; di < 4; ++di)
                *(f32x4*)(xch + xi + qi * 16 + di * 4) = acc[qi][di];
            *(f32x4*)(xch + xi + 32 + qi * 4) = lacc[qi];
        }
    }
    __syncthreads();
    if (wg == 0) {
        #pragma unroll
        for (int qi = 0; qi < 2; ++qi) {
            #pragma unroll
            for (int di = 0; di < 4; ++di)
                acc[qi][di] += *(const f32x4*)(xch + xi + qi * 16 + di * 4);
            lacc[qi] += *(const f32x4*)(xch + xi + 32 + qi * 4);
        }
        #pragma unroll
        for (int qi = 0; qi < 2; ++qi) {
            float inv[4];
            #pragma unroll
            for (int r = 0; r < 4; ++r) inv[r] = 1.0f / lacc[qi][r];
            #pragma unroll
            for (int di = 0; di < 4; ++di) {
                const int e = di * 16 + l15;
                #pragma unroll
                for (int r = 0; r < 4; ++r) {
                    const int qn = q0 + wv * 32 + qi * 16 + lg * 4 + r;
                    ob[((size_t)(b * SEQ + qn) << 9) + h * 64 + e] = f2bf(acc[qi][di][r] * inv[r]);
                }
            }
        }
    }
}

// ---------------- proj GEMM (bf16 via gload_lds) + bias + residual: y = x + ao@w^T + bp
__global__ __launch_bounds__(256) void proj_k(
    const short* __restrict__ ao, const short* __restrict__ wpb,
    const float* __restrict__ bp, const float* __restrict__ x,
    float* __restrict__ y)
{
    __shared__ alignas(16) short As[2][128 * 64];
    __shared__ alignas(16) short Bs[2][128 * 64];
    const int tid  = threadIdx.x;
    const int lane = tid & 63;
    const int l15  = lane & 15;
    const int lg   = lane >> 4;
    const int wv   = tid >> 6;
    const int wy   = wv >> 1, wx = wv & 1;
    const int m0 = blockIdx.x * 128;
    const int n0 = blockIdx.y * 128;

    const f32x4 fzero = {0.f, 0.f, 0.f, 0.f};
    f32x4 acc[4][4];
    #pragma unroll
    for (int i = 0; i < 4; ++i)
        #pragma unroll
        for (int j = 0; j < 4; ++j)
            acc[i][j] = fzero;

    const int row0 = wv * 8 + (lane >> 3);
    const int cb   = ((lane & 7) ^ (lane >> 3)) << 4;
    const char* agp = (const char*)ao  + (size_t)(m0 + row0) * 1024 + cb;
    const char* bgp = (const char*)wpb + (size_t)(n0 + row0) * 1024 + cb;
    char* al0 = (char*)&As[0][0] + wv * 1024;
    char* al1 = (char*)&As[1][0] + wv * 1024;
    char* bl0 = (char*)&Bs[0][0] + wv * 1024;
    char* bl1 = (char*)&Bs[1][0] + wv * 1024;

    #define PSTAGE(al, bl, kofs) do {                                  \
        _Pragma("unroll")                                              \
        for (int i_ = 0; i_ < 4; ++i_) {                               \
            gl16(agp + (kofs) + i_ * 32768, (al) + i_ * 4096);         \
            gl16(bgp + (kofs) + i_ * 32768, (bl) + i_ * 4096);         \
        } } while (0)

    PSTAGE(al0, bl0, 0);

    int cur = 0;
    for (int k0 = 0; k0 < CDIM; k0 += 64) {
        asm volatile("s_waitcnt vmcnt(0)" ::: "memory");
        __syncthreads();
        if (k0 + 64 < CDIM) {
            if (cur == 0) PSTAGE(al1, bl1, (k0 + 64) * 2);
            else          PSTAGE(al0, bl0, (k0 + 64) * 2);
        }
        const short* Ac = cur ? &As[1][0] : &As[0][0];
        const short* Bc = cur ? &Bs[1][0] : &Bs[0][0];

        #pragma unroll
        for (int ks = 0; ks < 2; ++ks) {
            bf16x8 afr[4], bfr[4];
            #pragma unroll
            for (int i = 0; i < 4; ++i) {
                afr[i] = *(const bf16x8*)(&Ac[swz(wy * 64 + i * 16 + l15, ks * 32 + lg * 8)]);
                bfr[i] = *(const bf16x8*)(&Bc[swz(wx * 64 + i * 16 + l15, ks * 32 + lg * 8)]);
            }
            #pragma unroll
            for (int i = 0; i < 4; ++i)
                #pragma unroll
                for (int j = 0; j < 4; ++j)
                    acc[i][j] = __builtin_amdgcn_mfma_f32_16x16x32_bf16(afr[i], bfr[j], acc[i][j], 0, 0, 0);
        }
        cur ^= 1;
    }
    #undef PSTAGE

    #pragma unroll
    for (int i = 0; i < 4; ++i) {
        #pragma unroll
        for (int j = 0; j < 4; ++j) {
            const int d = n0 + wx * 64 + j * 16 + l15;
            #pragma unroll
            for (int r = 0; r < 4; ++r) {
                const int m = m0 + wy * 64 + i * 16 + lg * 4 + r;
                const size_t idx = (size_t)m * CDIM + d;
                y[idx] = acc[i][j][r] + bp[d] + x[idx];
            }
        }
    }
}

// ---------------- LayerNorm in place over d_out rows (512 f32 each), 1 wave/row
__global__ __launch_bounds__(256) void ln_k(
    float* __restrict__ y, const float* __restrict__ gm, const float* __restrict__ bt)
{
    const int lane = threadIdx.x & 63;
    const int row  = blockIdx.x * 4 + (threadIdx.x >> 6);
    float* p = y + (size_t)row * CDIM;
    float4 a = *(const float4*)(p + lane * 4);
    float4 b = *(const float4*)(p + 256 + lane * 4);
    float s = a.x + a.y + a.z + a.w + b.x + b.y + b.z + b.w;
    float q = a.x * a.x + a.y * a.y + a.z * a.z + a.w * a.w
            + b.x * b.x + b.y * b.y + b.z * b.z + b.w * b.w;
    #pragma unroll
    for (int mm = 1; mm < 64; mm <<= 1) {
        s += __shfl_xor(s, mm, 64);
        q += __shfl_xor(q, mm, 64);
    }
    const float mean = s * (1.0f / CDIM);
    const float var  = q * (1.0f / CDIM) - mean * mean;
    const float inv  = rsqrtf(var + 1e-5f);
    float4 g0 = *(const float4*)(gm + lane * 4);
    float4 g1 = *(const float4*)(gm + 256 + lane * 4);
    float4 t0 = *(const float4*)(bt + lane * 4);
    float4 t1 = *(const float4*)(bt + 256 + lane * 4);
    float4 r0, r1;
    r0.x = (a.x - mean) * inv * g0.x + t0.x;
    r0.y = (a.y - mean) * inv * g0.y + t0.y;
    r0.z = (a.z - mean) * inv * g0.z + t0.z;
    r0.w = (a.w - mean) * inv * g0.w + t0.w;
    r1.x = (b.x - mean) * inv * g1.x + t1.x;
    r1.y = (b.y - mean) * inv * g1.y + t1.y;
    r1.z = (b.z - mean) * inv * g1.z + t1.z;
    r1.w = (b.w - mean) * inv * g1.w + t1.w;
    *(float4*)(p + lane * 4) = r0;
    *(float4*)(p + 256 + lane * 4) = r1;
}

extern "C" void kernel_launch(void* const* d_in, const int* in_sizes, int n_in,
                              void* d_out, int out_size, void* d_ws, size_t ws_size,
                              hipStream_t stream)
{
    const float* x      = (const float*)d_in[0];
    const float* w_qkv  = (const float*)d_in[1];
    const float* w_proj = (const float*)d_in[2];
    const float* b_proj = (const float*)d_in[3];
    const float* gamma  = (const float*)d_in[4];
    const float* beta   = (const float*)d_in[5];
    float* out = (float*)d_out;

    const size_t qkv_elems = (size_t)16 * SEQ * HDIM;
    short* qb    = (short*)d_ws;
    short* kb    = qb + qkv_elems;
    short* vtb   = kb + qkv_elems;
    short* ob    = vtb + qkv_elems;
    short* xb    = ob;                     // alias: xb dead before attn writes ob
    short* wqkvb = ob + qkv_elems;
    short* wpb   = qb;                     // alias: qb dead after attn

    cvt_k     <<<dim3(1024),   256, 0, stream>>>(x, xb, (2 * SEQ * CDIM) / 4);
    cvt_k     <<<dim3(256),    256, 0, stream>>>(w_qkv, wqkvb, (3 * CDIM * CDIM) / 4);
    qkv_gemm_k<<<dim3(64, 12), 256, 0, stream>>>(xb, wqkvb, qb, kb, vtb);
    attn_k    <<<dim3(512),    512, 0, stream>>>(qb, kb, vtb, ob);
    cvt_k     <<<dim3(256),    256, 0, stream>>>(w_proj, wpb, (CDIM * CDIM) / 4);
    proj_k    <<<dim3(64, 4),  256, 0, stream>>>(ob, wpb, b_proj, x, out);
    ln_k      <<<dim3(2048),   256, 0, stream>>>(out, gamma, beta);
}

// Round 12
// 117.506 us; speedup vs baseline: 2.4548x; 1.0376x over previous
//
#include <hip/hip_runtime.h>
#include <hip/hip_bf16.h>

#define SEQ    4096
#define CDIM   512
#define NHEADS 8
#define HDIM   64
// fold softmax scale and log2(e) into Q once: exp(s*SCALE) == exp2(s')
#define QSCALE 0.18033688f   // 0.125 * 1.4426950408889634

typedef __attribute__((ext_vector_type(4))) float f32x4;
typedef __attribute__((ext_vector_type(8))) short bf16x8;

// LDS swizzle for tiles with 64-bf16 (128B) row stride: spread rows across banks.
__device__ __forceinline__ int swz(int row, int col) {
    int b = (row << 7) + (col << 1);
    b ^= (row & 7) << 4;
    return b >> 1;
}

__device__ __forceinline__ short f2bf(float f) {
    union { __hip_bfloat16 h; short s; } u;
    u.h = __float2bfloat16(f);
    return u.s;
}

// async global->LDS, 16B per lane; LDS dest = wave-uniform base + lane*16
__device__ __forceinline__ void gl16(const void* g, void* l) {
    __builtin_amdgcn_global_load_lds(
        (const __attribute__((address_space(1))) unsigned int*)g,
        (__attribute__((address_space(3))) unsigned int*)l,
        16, 0, 0);
}

// ---------------- f32 -> bf16 pre-pass for all three arrays (one launch)
__global__ __launch_bounds__(256) void cvt3_k(
    const float* __restrict__ a0, short* __restrict__ o0, int c0,
    const float* __restrict__ a1, short* __restrict__ o1, int c1,
    const float* __restrict__ a2, short* __restrict__ o2, int c2)
{
    const int total = c0 + c1 + c2;
    int i = blockIdx.x * 256 + threadIdx.x;
    const int stride = gridDim.x * 256;
    for (; i < total; i += stride) {
        const float* a; short* o; int j;
        if (i < c0)           { a = a0; o = o0; j = i; }
        else if (i < c0 + c1) { a = a1; o = o1; j = i - c0; }
        else                  { a = a2; o = o2; j = i - c0 - c1; }
        float4 v = ((const float4*)a)[j];
        short4 r;
        r.x = f2bf(v.x); r.y = f2bf(v.y); r.z = f2bf(v.z); r.w = f2bf(v.w);
        ((short4*)o)[j] = r;
    }
}

// ---------------- QKV GEMM (bf16 inputs): xb[8192,512] @ wb[1536,512]^T
__global__ __launch_bounds__(256) void qkv_gemm_k(
    const short* __restrict__ xb, const short* __restrict__ wb,
    short* __restrict__ qb, short* __restrict__ kb, short* __restrict__ vtb)
{
    __shared__ alignas(16) short As[2][128 * 64];
    __shared__ alignas(16) short Bs[2][128 * 64];
    const int tid  = threadIdx.x;
    const int lane = tid & 63;
    const int l15  = lane & 15;
    const int lg   = lane >> 4;
    const int wv   = tid >> 6;
    const int wy   = wv >> 1, wx = wv & 1;
    const int m0 = blockIdx.x * 128;
    const int n0 = blockIdx.y * 128;

    const f32x4 fzero = {0.f, 0.f, 0.f, 0.f};
    f32x4 acc[4][4];
    #pragma unroll
    for (int i = 0; i < 4; ++i)
        #pragma unroll
        for (int j = 0; j < 4; ++j)
            acc[i][j] = fzero;

    const int row0 = wv * 8 + (lane >> 3);
    const int cb   = ((lane & 7) ^ (lane >> 3)) << 4;
    const char* agp = (const char*)xb + (size_t)(m0 + row0) * 1024 + cb;
    const char* bgp = (const char*)wb + (size_t)(n0 + row0) * 1024 + cb;
    char* al0 = (char*)&As[0][0] + wv * 1024;
    char* al1 = (char*)&As[1][0] + wv * 1024;
    char* bl0 = (char*)&Bs[0][0] + wv * 1024;
    char* bl1 = (char*)&Bs[1][0] + wv * 1024;

    #define QSTAGE(al, bl, kofs) do {                                  \
        _Pragma("unroll")                                              \
        for (int i_ = 0; i_ < 4; ++i_) {                               \
            gl16(agp + (kofs) + i_ * 32768, (al) + i_ * 4096);         \
            gl16(bgp + (kofs) + i_ * 32768, (bl) + i_ * 4096);         \
        } } while (0)

    QSTAGE(al0, bl0, 0);

    int cur = 0;
    for (int k0 = 0; k0 < CDIM; k0 += 64) {
        asm volatile("s_waitcnt vmcnt(0)" ::: "memory");
        __syncthreads();
        if (k0 + 64 < CDIM) {
            if (cur == 0) QSTAGE(al1, bl1, (k0 + 64) * 2);
            else          QSTAGE(al0, bl0, (k0 + 64) * 2);
        }
        const short* Ac = cur ? &As[1][0] : &As[0][0];
        const short* Bc = cur ? &Bs[1][0] : &Bs[0][0];

        #pragma unroll
        for (int ks = 0; ks < 2; ++ks) {
            bf16x8 afr[4], bfr[4];
            #pragma unroll
            for (int i = 0; i < 4; ++i) {
                afr[i] = *(const bf16x8*)(&Ac[swz(wy * 64 + i * 16 + l15, ks * 32 + lg * 8)]);
                bfr[i] = *(const bf16x8*)(&Bc[swz(wx * 64 + i * 16 + l15, ks * 32 + lg * 8)]);
            }
            #pragma unroll
            for (int i = 0; i < 4; ++i)
                #pragma unroll
                for (int j = 0; j < 4; ++j)
                    acc[i][j] = __builtin_amdgcn_mfma_f32_16x16x32_bf16(afr[i], bfr[j], acc[i][j], 0, 0, 0);
        }
        cur ^= 1;
    }
    #undef QSTAGE

    // epilogue: Q (scaled), K as [bh][n][64]; V^T blocked with col-perm
    #pragma unroll
    for (int j = 0; j < 4; ++j) {
        const int d = n0 + wx * 64 + j * 16 + l15;
        const int s = d >> 9;
        const int h = (d >> 6) & 7;
        const int e = d & 63;
        #pragma unroll
        for (int i = 0; i < 4; ++i) {
            #pragma unroll
            for (int r = 0; r < 4; ++r) {
                const int m  = m0 + wy * 64 + i * 16 + lg * 4 + r;
                const int bb = m >> 12;
                const int n  = m & (SEQ - 1);
                const int bh = bb * NHEADS + h;
                const float v = acc[i][j][r];
                if (s == 0) {
                    qb[(((size_t)bh * SEQ + n) << 6) + e] = f2bf(v * QSCALE);
                } else if (s == 1) {
                    kb[(((size_t)bh * SEQ + n) << 6) + e] = f2bf(v);
                } else {
                    // permute within-64 kv index: c=[ks|h|lg|j] -> c'=[ks|lg|h|j]
                    const int c  = n & 63;
                    const int cp = (c & 0x23) | ((c & 0x0C) << 1) | ((c & 0x10) >> 2);
                    vtb[((size_t)bh << 18) + ((size_t)(n >> 6) << 12) + (e << 6) + cp] = f2bf(v);
                }
            }
        }
    }
}

// ---------------- Flash attention v8: split-KV + fused QK->exp2 + PV interleave
//   + ANTI-PHASE TILE STAGGER: co-resident block pairs (lin, lin+256) visit kv
//   tiles 16 apart (order-invariant under fixed-base softmax) so one block's
//   exp2 phase overlaps the other's MFMA phase on the shared CU pipes.
__global__ __launch_bounds__(512) void attn_k(
    const short* __restrict__ qb, const short* __restrict__ kb, const short* __restrict__ vtb,
    short* __restrict__ ob)
{
    __shared__ alignas(16) char smem[81920];
    const int tid  = threadIdx.x;
    const int lane = tid & 63;
    const int l15  = lane & 15;
    const int lg   = lane >> 4;
    const int wv   = (tid >> 6) & 3;    // wave within group
    const int wg   = tid >> 8;          // wave group = kv half
    const int lin  = blockIdx.x;
    const int bh   = lin & 15;          // same-bh blocks land on one XCD (L2 locality)
    const int q0   = (lin >> 4) << 7;   // 128 q-rows per block
    const int b    = bh >> 3, h = bh & 7;
    const int phase = ((lin >> 8) & 1) << 4;   // anti-phase for CU-sharing block pair
    const size_t base = (size_t)bh * SEQ * HDIM;

    // Q fragments: wave owns 32 q-rows (2 fragments of 16); both groups same Q
    bf16x8 qf[2][2];
    #pragma unroll
    for (int qi = 0; qi < 2; ++qi) {
        const short* qp = qb + base + (size_t)(q0 + wv * 32 + qi * 16 + l15) * HDIM + lg * 8;
        qf[qi][0] = *(const bf16x8*)(qp);
        qf[qi][1] = *(const bf16x8*)(qp + 32);
    }

    const f32x4 fzero = {0.f, 0.f, 0.f, 0.f};
    f32x4 acc[2][4];    // partial O for this kv half
    f32x4 lacc[2];      // partial row sums via ones-MFMA
    #pragma unroll
    for (int qi = 0; qi < 2; ++qi) {
        lacc[qi] = fzero;
        #pragma unroll
        for (int di = 0; di < 4; ++di) acc[qi][di] = fzero;
    }

    bf16x8 ones;
    #pragma unroll
    for (int e = 0; e < 8; ++e) ones[e] = (short)0x3F80;  // bf16 1.0

    // staging: per-group 8KB K dbuf x2 + 8KB V x3; slot t = wv*128 + i*64 + lane
    const int t0  = wv * 128 + lane;
    const int cbs = ((t0 & 7) ^ ((t0 >> 3) & 7)) << 4;
    const int ghb = wg * 262144;   // group's kv-half byte offset (2048 kv * 128B)
    const char* kgp = (const char*)(kb + base) + ghb + (((t0 >> 3) << 7) + cbs);
    const char* vgp = (const char*)(vtb + ((size_t)bh << 18)) + ghb + (((t0 >> 3) << 7) + cbs);
    char* const gb = smem + wg * 40960;
    char* K0p = gb +     0 + wv * 2048;  const short* Kr0 = (const short*)(gb);
    char* K1p = gb +  8192 + wv * 2048;  const short* Kr1 = (const short*)(gb + 8192);
    char* V0p = gb + 16384 + wv * 2048;  const short* Vr0 = (const short*)(gb + 16384);
    char* V1p = gb + 24576 + wv * 2048;  const short* Vr1 = (const short*)(gb + 24576);
    char* V2p = gb + 32768 + wv * 2048;  const short* Vr2 = (const short*)(gb + 32768);

    bf16x8 paA[2][2], paB[2][2];

    // visit order: tile(i) = (phase + i) & 31; TOFS gives the byte offset
    #define TOFS(T) (((phase + (T)) & 31) * 8192)

    #define STAGE(klp, vlp, BOFS) do {                                     \
        _Pragma("unroll")                                                  \
        for (int i_ = 0; i_ < 2; ++i_) {                                   \
            gl16(kgp + (BOFS) + i_ * 1024, (klp) + i_ * 1024);             \
            gl16(vgp + (BOFS) + i_ * 1024, (vlp) + i_ * 1024);             \
        } } while (0)

    #define MFMA16(a_, b_, c_) __builtin_amdgcn_mfma_f32_16x16x32_bf16(a_, b_, c_, 0, 0, 0)

    // BODY(t): QK(ni)->exp2(ni) fused, PV(t-1) MFMAs interleaved between them.
    #define BODY(TILE, KRD, VPR, KSTP, VSTP, PAP, PAN, DOSTG) do {             \
        asm volatile("s_waitcnt vmcnt(0)" ::: "memory");                       \
        __syncthreads();                                                       \
        if (DOSTG) { STAGE(KSTP, VSTP, TOFS((TILE) + 1)); }                    \
        _Pragma("unroll")                                                      \
        for (int ni = 0; ni < 4; ++ni) {                                       \
            bf16x8 kf0 = *(const bf16x8*)(&(KRD)[swz(ni * 16 + l15, lg * 8)]);      \
            bf16x8 kf1 = *(const bf16x8*)(&(KRD)[swz(ni * 16 + l15, 32 + lg * 8)]); \
            f32x4 s0 = fzero, s1 = fzero;                                      \
            s0 = MFMA16(kf0, qf[0][0], s0);                                    \
            s0 = MFMA16(kf1, qf[0][1], s0);                                    \
            s1 = MFMA16(kf0, qf[1][0], s1);                                    \
            s1 = MFMA16(kf1, qf[1][1], s1);                                    \
            bf16x8 v0 = *(const bf16x8*)(&(VPR)[swz(ni * 16 + l15, lg * 8)]);       \
            bf16x8 v1 = *(const bf16x8*)(&(VPR)[swz(ni * 16 + l15, 32 + lg * 8)]);  \
            acc[0][ni] = MFMA16(PAP[0][0], v0, acc[0][ni]);                    \
            acc[0][ni] = MFMA16(PAP[0][1], v1, acc[0][ni]);                    \
            acc[1][ni] = MFMA16(PAP[1][0], v0, acc[1][ni]);                    \
            acc[1][ni] = MFMA16(PAP[1][1], v1, acc[1][ni]);                    \
            if (ni == 0) { lacc[0] = MFMA16(PAP[0][0], ones, lacc[0]);         \
                           lacc[0] = MFMA16(PAP[0][1], ones, lacc[0]); }       \
            if (ni == 1) { lacc[1] = MFMA16(PAP[1][0], ones, lacc[1]);         \
                           lacc[1] = MFMA16(PAP[1][1], ones, lacc[1]); }       \
            _Pragma("unroll")                                                  \
            for (int r = 0; r < 4; ++r) {                                      \
                PAN[0][ni >> 1][(ni & 1) * 4 + r] = f2bf(__builtin_amdgcn_exp2f(s0[r])); \
                PAN[1][ni >> 1][(ni & 1) * 4 + r] = f2bf(__builtin_amdgcn_exp2f(s1[r])); \
            }                                                                  \
        }                                                                      \
    } while (0)

    // prologue: first tile (QK + exp2 only, into paA)
    STAGE(K0p, V0p, TOFS(0));
    asm volatile("s_waitcnt vmcnt(0)" ::: "memory");
    __syncthreads();
    STAGE(K1p, V1p, TOFS(1));
    #pragma unroll
    for (int ni = 0; ni < 4; ++ni) {
        bf16x8 kf0 = *(const bf16x8*)(&Kr0[swz(ni * 16 + l15, lg * 8)]);
        bf16x8 kf1 = *(const bf16x8*)(&Kr0[swz(ni * 16 + l15, 32 + lg * 8)]);
        f32x4 s0 = fzero, s1 = fzero;
        s0 = MFMA16(kf0, qf[0][0], s0);
        s0 = MFMA16(kf1, qf[0][1], s0);
        s1 = MFMA16(kf0, qf[1][0], s1);
        s1 = MFMA16(kf1, qf[1][1], s1);
        #pragma unroll
        for (int r = 0; r < 4; ++r) {
            paA[0][ni >> 1][(ni & 1) * 4 + r] = f2bf(__builtin_amdgcn_exp2f(s0[r]));
            paA[1][ni >> 1][(ni & 1) * 4 + r] = f2bf(__builtin_amdgcn_exp2f(s1[r]));
        }
    }

    // main: steps 1..30 in 6-unrolled groups (periodic buffer pattern), then 31
    for (int i = 0; i < 5; ++i) {
        BODY(6 * i + 1, Kr1, Vr0, K0p, V2p, paA, paB, 1);
        BODY(6 * i + 2, Kr0, Vr1, K1p, V0p, paB, paA, 1);
        BODY(6 * i + 3, Kr1, Vr2, K0p, V1p, paA, paB, 1);
        BODY(6 * i + 4, Kr0, Vr0, K1p, V2p, paB, paA, 1);
        BODY(6 * i + 5, Kr1, Vr1, K0p, V0p, paA, paB, 1);
        BODY(6 * i + 6, Kr0, Vr2, K1p, V1p, paB, paA, 1);
    }
    BODY(31, Kr1, Vr0, K0p, V2p, paA, paB, 0);

    // epilogue PV for last step (pa=paB, V=Vr1)
    #pragma unroll
    for (int dd = 0; dd < 4; ++dd) {
        bf16x8 v0 = *(const bf16x8*)(&Vr1[swz(dd * 16 + l15, lg * 8)]);
        bf16x8 v1 = *(const bf16x8*)(&Vr1[swz(dd * 16 + l15, 32 + lg * 8)]);
        acc[0][dd] = MFMA16(paB[0][0], v0, acc[0][dd]);
        acc[0][dd] = MFMA16(paB[0][1], v1, acc[0][dd]);
        acc[1][dd] = MFMA16(paB[1][0], v0, acc[1][dd]);
        acc[1][dd] = MFMA16(paB[1][1], v1, acc[1][dd]);
    }
    lacc[0] = MFMA16(paB[0][0], ones, lacc[0]);
    lacc[0] = MFMA16(paB[0][1], ones, lacc[0]);
    lacc[1] = MFMA16(paB[1][0], ones, lacc[1]);
    lacc[1] = MFMA16(paB[1][1], ones, lacc[1]);
    #undef BODY
    #undef MFMA16
    #undef STAGE
    #undef TOFS

    // ---- combine the two kv-halves: O = (O0+O1)/(l0+l1) ----
    __syncthreads();   // all K/V reads done; smem reusable as f32 exchange buffer
    float* xch = (float*)smem;
    const int xi = (wv * 64 + lane) * 44;   // 44 f32 stride: 16B-aligned, bank-spread
    if (wg == 1) {
        #pragma unroll
        for (int qi = 0; qi < 2; ++qi) {
            #pragma unroll
            for (int di = 0; di < 4; ++di)
                *(f32x4*)(xch + xi + qi * 16 + di * 4) = acc[qi][di];
            *(f32x4*)(xch + xi + 32 + qi * 4) = lacc[qi];
        }
    }
    __syncthreads();
    if (wg == 0) {
        #pragma unroll
        for (int qi = 0; qi < 2; ++qi) {
            #pragma unroll
            for (int di = 0; di < 4; ++di)
                acc[qi][di] += *(const f32x4*)(xch + xi + qi * 16 + di * 4);
            lacc[qi] += *(const f32x4*)(xch + xi + 32 + qi * 4);
        }
        #pragma unroll
        for (int qi = 0; qi < 2; ++qi) {
            float inv[4];
            #pragma unroll
            for (int r = 0; r < 4; ++r) inv[r] = 1.0f / lacc[qi][r];
            #pragma unroll
            for (int di = 0; di < 4; ++di) {
                const int e = di * 16 + l15;
                #pragma unroll
                for (int r = 0; r < 4; ++r) {
                    const int qn = q0 + wv * 32 + qi * 16 + lg * 4 + r;
                    ob[((size_t)(b * SEQ + qn) << 9) + h * 64 + e] = f2bf(acc[qi][di][r] * inv[r]);
                }
            }
        }
    }
}

// ---------------- proj GEMM (bf16 via gload_lds) + bias + residual: y = x + ao@w^T + bp
__global__ __launch_bounds__(256) void proj_k(
    const short* __restrict__ ao, const short* __restrict__ wpb,
    const float* __restrict__ bp, const float* __restrict__ x,
    float* __restrict__ y)
{
    __shared__ alignas(16) short As[2][128 * 64];
    __shared__ alignas(16) short Bs[2][128 * 64];
    const int tid  = threadIdx.x;
    const int lane = tid & 63;
    const int l15  = lane & 15;
    const int lg   = lane >> 4;
    const int wv   = tid >> 6;
    const int wy   = wv >> 1, wx = wv & 1;
    const int m0 = blockIdx.x * 128;
    const int n0 = blockIdx.y * 128;

    const f32x4 fzero = {0.f, 0.f, 0.f, 0.f};
    f32x4 acc[4][4];
    #pragma unroll
    for (int i = 0; i < 4; ++i)
        #pragma unroll
        for (int j = 0; j < 4; ++j)
            acc[i][j] = fzero;

    const int row0 = wv * 8 + (lane >> 3);
    const int cb   = ((lane & 7) ^ (lane >> 3)) << 4;
    const char* agp = (const char*)ao  + (size_t)(m0 + row0) * 1024 + cb;
    const char* bgp = (const char*)wpb + (size_t)(n0 + row0) * 1024 + cb;
    char* al0 = (char*)&As[0][0] + wv * 1024;
    char* al1 = (char*)&As[1][0] + wv * 1024;
    char* bl0 = (char*)&Bs[0][0] + wv * 1024;
    char* bl1 = (char*)&Bs[1][0] + wv * 1024;

    #define PSTAGE(al, bl, kofs) do {                                  \
        _Pragma("unroll")                                              \
        for (int i_ = 0; i_ < 4; ++i_) {                               \
            gl16(agp + (kofs) + i_ * 32768, (al) + i_ * 4096);         \
            gl16(bgp + (kofs) + i_ * 32768, (bl) + i_ * 4096);         \
        } } while (0)

    PSTAGE(al0, bl0, 0);

    int cur = 0;
    for (int k0 = 0; k0 < CDIM; k0 += 64) {
        asm volatile("s_waitcnt vmcnt(0)" ::: "memory");
        __syncthreads();
        if (k0 + 64 < CDIM) {
            if (cur == 0) PSTAGE(al1, bl1, (k0 + 64) * 2);
            else          PSTAGE(al0, bl0, (k0 + 64) * 2);
        }
        const short* Ac = cur ? &As[1][0] : &As[0][0];
        const short* Bc = cur ? &Bs[1][0] : &Bs[0][0];

        #pragma unroll
        for (int ks = 0; ks < 2; ++ks) {
            bf16x8 afr[4], bfr[4];
            #pragma unroll
            for (int i = 0; i < 4; ++i) {
                afr[i] = *(const bf16x8*)(&Ac[swz(wy * 64 + i * 16 + l15, ks * 32 + lg * 8)]);
                bfr[i] = *(const bf16x8*)(&Bc[swz(wx * 64 + i * 16 + l15, ks * 32 + lg * 8)]);
            }
            #pragma unroll
            for (int i = 0; i < 4; ++i)
                #pragma unroll
                for (int j = 0; j < 4; ++j)
                    acc[i][j] = __builtin_amdgcn_mfma_f32_16x16x32_bf16(afr[i], bfr[j], acc[i][j], 0, 0, 0);
        }
        cur ^= 1;
    }
    #undef PSTAGE

    #pragma unroll
    for (int i = 0; i < 4; ++i) {
        #pragma unroll
        for (int j = 0; j < 4; ++j) {
            const int d = n0 + wx * 64 + j * 16 + l15;
            #pragma unroll
            for (int r = 0; r < 4; ++r) {
                const int m = m0 + wy * 64 + i * 16 + lg * 4 + r;
                const size_t idx = (size_t)m * CDIM + d;
                y[idx] = acc[i][j][r] + bp[d] + x[idx];
            }
        }
    }
}

// ---------------- LayerNorm in place over d_out rows (512 f32 each), 1 wave/row
__global__ __launch_bounds__(256) void ln_k(
    float* __restrict__ y, const float* __restrict__ gm, const float* __restrict__ bt)
{
    const int lane = threadIdx.x & 63;
    const int row  = blockIdx.x * 4 + (threadIdx.x >> 6);
    float* p = y + (size_t)row * CDIM;
    float4 a = *(const float4*)(p + lane * 4);
    float4 b = *(const float4*)(p + 256 + lane * 4);
    float s = a.x + a.y + a.z + a.w + b.x + b.y + b.z + b.w;
    float q = a.x * a.x + a.y * a.y + a.z * a.z + a.w * a.w
            + b.x * b.x + b.y * b.y + b.z * b.z + b.w * b.w;
    #pragma unroll
    for (int mm = 1; mm < 64; mm <<= 1) {
        s += __shfl_xor(s, mm, 64);
        q += __shfl_xor(q, mm, 64);
    }
    const float mean = s * (1.0f / CDIM);
    const float var  = q * (1.0f / CDIM) - mean * mean;
    const float inv  = rsqrtf(var + 1e-5f);
    float4 g0 = *(const float4*)(gm + lane * 4);
    float4 g1 = *(const float4*)(gm + 256 + lane * 4);
    float4 t0 = *(const float4*)(bt + lane * 4);
    float4 t1 = *(const float4*)(bt + 256 + lane * 4);
    float4 r0, r1;
    r0.x = (a.x - mean) * inv * g0.x + t0.x;
    r0.y = (a.y - mean) * inv * g0.y + t0.y;
    r0.z = (a.z - mean) * inv * g0.z + t0.z;
    r0.w = (a.w - mean) * inv * g0.w + t0.w;
    r1.x = (b.x - mean) * inv * g1.x + t1.x;
    r1.y = (b.y - mean) * inv * g1.y + t1.y;
    r1.z = (b.z - mean) * inv * g1.z + t1.z;
    r1.w = (b.w - mean) * inv * g1.w + t1.w;
    *(float4*)(p + lane * 4) = r0;
    *(float4*)(p + 256 + lane * 4) = r1;
}

extern "C" void kernel_launch(void* const* d_in, const int* in_sizes, int n_in,
                              void* d_out, int out_size, void* d_ws, size_t ws_size,
                              hipStream_t stream)
{
    const float* x      = (const float*)d_in[0];
    const float* w_qkv  = (const float*)d_in[1];
    const float* w_proj = (const float*)d_in[2];
    const float* b_proj = (const float*)d_in[3];
    const float* gamma  = (const float*)d_in[4];
    const float* beta   = (const float*)d_in[5];
    float* out = (float*)d_out;

    // workspace layout (shorts): qb,kb,vtb,ob = 4 x 4.19M; xb aliases ob;
    // wqkvb (0.79M) and wpb (0.26M) after. Total ~35.7 MB.
    const size_t qkv_elems = (size_t)16 * SEQ * HDIM;
    short* qb    = (short*)d_ws;
    short* kb    = qb + qkv_elems;
    short* vtb   = kb + qkv_elems;
    short* ob    = vtb + qkv_elems;
    short* xb    = ob;                     // alias: xb dead before attn writes ob
    short* wqkvb = ob + qkv_elems;
    short* wpb   = wqkvb + (size_t)3 * CDIM * CDIM;

    cvt3_k    <<<dim3(1024),   256, 0, stream>>>(
        x, xb, (2 * SEQ * CDIM) / 4,
        w_qkv, wqkvb, (3 * CDIM * CDIM) / 4,
        w_proj, wpb, (CDIM * CDIM) / 4);
    qkv_gemm_k<<<dim3(64, 12), 256, 0, stream>>>(xb, wqkvb, qb, kb, vtb);
    attn_k    <<<dim3(512),    512, 0, stream>>>(qb, kb, vtb, ob);
    proj_k    <<<dim3(64, 4),  256, 0, stream>>>(ob, wpb, b_proj, x, out);
    ln_k      <<<dim3(2048),   256, 0, stream>>>(out, gamma, beta);
}